// Round 1
// baseline (87.582 us; speedup 1.0000x reference)
//
#include <hip/hip_runtime.h>
#include <math.h>

namespace {

constexpr int Bn = 2, Hn = 128, Wn = 128, Cn = 256, Vn = 64;
constexpr int KS = 5;
constexpr int TW = 32;          // pixels per block
constexpr int COLS = TW + 4;    // 36 staged columns (with halo)
constexpr int RSTR = 67;        // LDS row stride in floats: bank (3p+8s)%32 -> 2-way max (free)
constexpr int TPB = 256;        // 32 pixels x 8 splits

__global__ __launch_bounds__(TPB, 4)
void local_attn_kernel(const float* __restrict__ mainp,
                       const float* __restrict__ mainv,
                       const float* __restrict__ refp,
                       const float* __restrict__ refv,
                       float* __restrict__ outp)
{
    const int t = threadIdx.x;
    const int s = t & 7;        // split 0..7
    const int p = t >> 3;       // pixel within tile 0..31

    const int blk = blockIdx.x;          // 0 .. B*H*4 - 1
    const int wt  = blk & 3;
    const int h   = (blk >> 2) & (Hn - 1);
    const int b   = blk >> 9;
    const int w0  = wt * TW;
    const int w   = w0 + p;

    __shared__ float lds[COLS * RSTR];   // 36*67*4 = 9.6 KB, reused for ref and ref_value

    float scores[26];
    #pragma unroll
    for (int k = 0; k < 26; ++k) scores[k] = 0.f;

    const int rowbase = (b * Hn + h) * Wn;
    const float* mrow = mainp + (size_t)rowbase * Cn;

    // ---------------- score phase ----------------
    // 4 passes over channels; each pass stages 64 consecutive channels of the 5 ref rows.
    for (int cc = 0; cc < 4; ++cc) {
        // this thread's 8 main channels for this pass
        float mreg[8];
        const float* mp = mrow + (size_t)w * Cn + cc * 64 + s * 8;
        {
            float4 v0 = *(const float4*)(mp + 0);
            float4 v1 = *(const float4*)(mp + 4);
            mreg[0]=v0.x; mreg[1]=v0.y; mreg[2]=v0.z; mreg[3]=v0.w;
            mreg[4]=v1.x; mreg[5]=v1.y; mreg[6]=v1.z; mreg[7]=v1.w;
        }
        #pragma unroll
        for (int c = 0; c < 8; ++c) scores[25] = fmaf(mreg[c], mreg[c], scores[25]);

        for (int di = 0; di < KS; ++di) {
            const int hh = h + di - 2;
            const float* srcrow = (hh >= 0 && hh < Hn)
                ? refp + ((size_t)(b * Hn + hh) * Wn) * Cn + cc * 64 : nullptr;
            __syncthreads();
            // stage [COLS][64] floats (zero padded)
            for (int q = t; q < COLS * 16; q += TPB) {
                const int pos = q >> 4, quad = q & 15;
                const int col = w0 + pos - 2;
                float4 v = make_float4(0.f, 0.f, 0.f, 0.f);
                if (srcrow && (unsigned)col < (unsigned)Wn)
                    v = *(const float4*)(srcrow + (size_t)col * Cn + quad * 4);
                float* d = lds + pos * RSTR + quad * 4;
                d[0]=v.x; d[1]=v.y; d[2]=v.z; d[3]=v.w;
            }
            __syncthreads();
            #pragma unroll
            for (int dj = 0; dj < KS; ++dj) {
                const float* lp = lds + (p + dj) * RSTR + s * 8;
                float acc = 0.f;
                #pragma unroll
                for (int c = 0; c < 8; ++c) acc = fmaf(mreg[c], lp[c], acc);
                scores[di * 5 + dj] += acc;
            }
        }
    }

    // reduce partial scores across the 8 split lanes (adjacent lanes of the wave)
    #pragma unroll
    for (int k = 0; k < 26; ++k) {
        float v = scores[k];
        v += __shfl_xor(v, 1);
        v += __shfl_xor(v, 2);
        v += __shfl_xor(v, 4);
        scores[k] = v;
    }

    // softmax over 26 slots (self slot is index 25, matching the reference concat order)
    float m = scores[0];
    #pragma unroll
    for (int k = 1; k < 26; ++k) m = fmaxf(m, scores[k]);
    float wts[26];
    float den = 0.f;
    #pragma unroll
    for (int k = 0; k < 26; ++k) { wts[k] = __expf(scores[k] - m); den += wts[k]; }
    const float inv = 1.f / den;

    // ---------------- value phase ----------------
    float acc[8];
    {
        const float* mvp = mainv + ((size_t)rowbase + w) * Vn + s * 8;
        float4 v0 = *(const float4*)(mvp + 0);
        float4 v1 = *(const float4*)(mvp + 4);
        acc[0]=wts[25]*v0.x; acc[1]=wts[25]*v0.y; acc[2]=wts[25]*v0.z; acc[3]=wts[25]*v0.w;
        acc[4]=wts[25]*v1.x; acc[5]=wts[25]*v1.y; acc[6]=wts[25]*v1.z; acc[7]=wts[25]*v1.w;
    }

    for (int di = 0; di < KS; ++di) {
        const int hh = h + di - 2;
        const float* srcrow = (hh >= 0 && hh < Hn)
            ? refv + ((size_t)(b * Hn + hh) * Wn) * Vn : nullptr;
        __syncthreads();
        for (int q = t; q < COLS * 16; q += TPB) {
            const int pos = q >> 4, quad = q & 15;
            const int col = w0 + pos - 2;
            float4 v = make_float4(0.f, 0.f, 0.f, 0.f);
            if (srcrow && (unsigned)col < (unsigned)Wn)
                v = *(const float4*)(srcrow + (size_t)col * Vn + quad * 4);
            float* d = lds + pos * RSTR + quad * 4;
            d[0]=v.x; d[1]=v.y; d[2]=v.z; d[3]=v.w;
        }
        __syncthreads();
        #pragma unroll
        for (int dj = 0; dj < KS; ++dj) {
            const float wk = wts[di * 5 + dj];
            const float* lp = lds + (p + dj) * RSTR + s * 8;
            #pragma unroll
            for (int c = 0; c < 8; ++c) acc[c] = fmaf(wk, lp[c], acc[c]);
        }
    }

    float* op = outp + ((size_t)rowbase + w) * Vn + s * 8;
    float4 o0, o1;
    o0.x = acc[0]*inv; o0.y = acc[1]*inv; o0.z = acc[2]*inv; o0.w = acc[3]*inv;
    o1.x = acc[4]*inv; o1.y = acc[5]*inv; o1.z = acc[6]*inv; o1.w = acc[7]*inv;
    *(float4*)(op + 0) = o0;
    *(float4*)(op + 4) = o1;
}

} // namespace

extern "C" void kernel_launch(void* const* d_in, const int* in_sizes, int n_in,
                              void* d_out, int out_size, void* d_ws, size_t ws_size,
                              hipStream_t stream)
{
    const float* mainp = (const float*)d_in[0];
    const float* mainv = (const float*)d_in[1];
    const float* refp  = (const float*)d_in[2];
    const float* refv  = (const float*)d_in[3];
    float* outp = (float*)d_out;

    dim3 grid(Bn * Hn * (Wn / TW));   // 1024 blocks
    dim3 block(TPB);
    hipLaunchKernelGGL(local_attn_kernel, grid, block, 0, stream,
                       mainp, mainv, refp, refv, outp);
}

// Round 2
// 52.556 us; speedup vs baseline: 1.6664x; 1.6664x over previous
//
#include <hip/hip_runtime.h>
#include <math.h>

namespace {

constexpr int Bn = 2, Hn = 128, Wn = 128, Cn = 256, Vn = 64;

__device__ __forceinline__ void load8(float* r, const float* p) {
    float4 v0 = *(const float4*)(p);
    float4 v1 = *(const float4*)(p + 4);
    r[0]=v0.x; r[1]=v0.y; r[2]=v0.z; r[3]=v0.w;
    r[4]=v1.x; r[5]=v1.y; r[6]=v1.z; r[7]=v1.w;
}

// Block = 64 consecutive pixels of one row. 256 threads = 32 pixel-pairs x 8
// channel-splits. Each lane owns 2 pixels x 8 channels. No LDS, no barriers:
// dj-reuse is captured in registers (each loaded ref float8 feeds up to 2
// pixels' scores), L1 serves the 3x overlap between neighboring pixel-pairs.
__global__ __launch_bounds__(256)
void local_attn_kernel(const float* __restrict__ mainp,
                       const float* __restrict__ mainv,
                       const float* __restrict__ refp,
                       const float* __restrict__ refv,
                       float* __restrict__ outp)
{
    const int t = threadIdx.x;
    const int s = t & 7;        // channel split 0..7
    const int g = t >> 3;       // pixel-pair 0..31
    const int blk = blockIdx.x; // 0 .. B*H*2-1
    const int half = blk & 1;
    const int h = (blk >> 1) & (Hn - 1);
    const int b = blk >> 8;
    const int w0 = half * 64 + g * 2;   // px0 = w0, px1 = w0+1

    float sc0[26], sc1[26];             // slot 25 = self (reference concat order)
    #pragma unroll
    for (int k = 0; k < 26; ++k) { sc0[k] = 0.f; sc1[k] = 0.f; }

    const int rowbase = b * Hn + h;

    // ---------------- score phase ----------------
    #pragma unroll 1
    for (int cc = 0; cc < 4; ++cc) {
        float m0[8], m1[8];
        const float* mp = mainp + ((size_t)rowbase * Wn + w0) * Cn + cc * 64 + s * 8;
        load8(m0, mp);
        load8(m1, mp + Cn);
        #pragma unroll
        for (int c = 0; c < 8; ++c) {
            sc0[25] = fmaf(m0[c], m0[c], sc0[25]);
            sc1[25] = fmaf(m1[c], m1[c], sc1[25]);
        }

        #pragma unroll
        for (int di = 0; di < 5; ++di) {
            const int hh = h + di - 2;
            const bool rowok = (unsigned)hh < (unsigned)Hn;
            const int hhc = rowok ? hh : 0;
            const float* rp = refp + ((size_t)(b * Hn + hhc) * Wn) * Cn + cc * 64 + s * 8;
            #pragma unroll
            for (int o = 0; o < 6; ++o) {
                const int col = w0 - 2 + o;
                float r[8];
                #pragma unroll
                for (int c = 0; c < 8; ++c) r[c] = 0.f;
                if (rowok && (unsigned)col < (unsigned)Wn)
                    load8(r, rp + (size_t)col * Cn);
                if (o < 5) {                      // contributes to px0, dj = o
                    float a = 0.f;
                    #pragma unroll
                    for (int c = 0; c < 8; ++c) a = fmaf(m0[c], r[c], a);
                    sc0[di * 5 + o] += a;
                }
                if (o >= 1) {                     // contributes to px1, dj = o-1
                    float a = 0.f;
                    #pragma unroll
                    for (int c = 0; c < 8; ++c) a = fmaf(m1[c], r[c], a);
                    sc1[di * 5 + (o - 1)] += a;
                }
            }
        }
    }

    // reduce partial dot products across the 8 split lanes (lane bits 0..2)
    #pragma unroll
    for (int k = 0; k < 26; ++k) {
        float v0 = sc0[k], v1 = sc1[k];
        v0 += __shfl_xor(v0, 1); v0 += __shfl_xor(v0, 2); v0 += __shfl_xor(v0, 4);
        v1 += __shfl_xor(v1, 1); v1 += __shfl_xor(v1, 2); v1 += __shfl_xor(v1, 4);
        sc0[k] = v0; sc1[k] = v1;
    }

    // softmax over 26 slots, per pixel (all split lanes redundantly)
    float mx0 = sc0[0], mx1 = sc1[0];
    #pragma unroll
    for (int k = 1; k < 26; ++k) { mx0 = fmaxf(mx0, sc0[k]); mx1 = fmaxf(mx1, sc1[k]); }
    float den0 = 0.f, den1 = 0.f;
    #pragma unroll
    for (int k = 0; k < 26; ++k) {
        sc0[k] = __expf(sc0[k] - mx0); den0 += sc0[k];
        sc1[k] = __expf(sc1[k] - mx1); den1 += sc1[k];
    }
    const float inv0 = 1.f / den0, inv1 = 1.f / den1;

    // ---------------- value phase ----------------
    float a0[8], a1[8];
    {
        const float* mvp = mainv + ((size_t)rowbase * Wn + w0) * Vn + s * 8;
        float v0[8], v1[8];
        load8(v0, mvp);
        load8(v1, mvp + Vn);
        #pragma unroll
        for (int c = 0; c < 8; ++c) { a0[c] = sc0[25] * v0[c]; a1[c] = sc1[25] * v1[c]; }
    }

    #pragma unroll
    for (int di = 0; di < 5; ++di) {
        const int hh = h + di - 2;
        const bool rowok = (unsigned)hh < (unsigned)Hn;
        const int hhc = rowok ? hh : 0;
        const float* rvp = refv + ((size_t)(b * Hn + hhc) * Wn) * Vn + s * 8;
        #pragma unroll
        for (int o = 0; o < 6; ++o) {
            const int col = w0 - 2 + o;
            float r[8];
            #pragma unroll
            for (int c = 0; c < 8; ++c) r[c] = 0.f;
            if (rowok && (unsigned)col < (unsigned)Wn)
                load8(r, rvp + (size_t)col * Vn);
            if (o < 5) {
                const float wk = sc0[di * 5 + o];
                #pragma unroll
                for (int c = 0; c < 8; ++c) a0[c] = fmaf(wk, r[c], a0[c]);
            }
            if (o >= 1) {
                const float wk = sc1[di * 5 + (o - 1)];
                #pragma unroll
                for (int c = 0; c < 8; ++c) a1[c] = fmaf(wk, r[c], a1[c]);
            }
        }
    }

    float* op = outp + ((size_t)rowbase * Wn + w0) * Vn + s * 8;
    float4 o00, o01, o10, o11;
    o00.x = a0[0]*inv0; o00.y = a0[1]*inv0; o00.z = a0[2]*inv0; o00.w = a0[3]*inv0;
    o01.x = a0[4]*inv0; o01.y = a0[5]*inv0; o01.z = a0[6]*inv0; o01.w = a0[7]*inv0;
    o10.x = a1[0]*inv1; o10.y = a1[1]*inv1; o10.z = a1[2]*inv1; o10.w = a1[3]*inv1;
    o11.x = a1[4]*inv1; o11.y = a1[5]*inv1; o11.z = a1[6]*inv1; o11.w = a1[7]*inv1;
    *(float4*)(op + 0) = o00;
    *(float4*)(op + 4) = o01;
    *(float4*)(op + Vn + 0) = o10;
    *(float4*)(op + Vn + 4) = o11;
}

} // namespace

extern "C" void kernel_launch(void* const* d_in, const int* in_sizes, int n_in,
                              void* d_out, int out_size, void* d_ws, size_t ws_size,
                              hipStream_t stream)
{
    const float* mainp = (const float*)d_in[0];
    const float* mainv = (const float*)d_in[1];
    const float* refp  = (const float*)d_in[2];
    const float* refv  = (const float*)d_in[3];
    float* outp = (float*)d_out;

    dim3 grid(Bn * Hn * 2);   // 512 blocks: one per 64-pixel row segment
    dim3 block(256);
    hipLaunchKernelGGL(local_attn_kernel, grid, block, 0, stream,
                       mainp, mainv, refp, refv, outp);
}